// Round 1
// baseline (383.583 us; speedup 1.0000x reference)
//
#include <hip/hip_runtime.h>
#include <hip/hip_bf16.h>

#define DEVI __device__ __forceinline__

typedef __attribute__((ext_vector_type(8))) short short8v;
typedef __attribute__((ext_vector_type(4))) float f32x4;

DEVI short f2bf(float f) {
  __hip_bfloat16 h = __float2bfloat16(f);
  return __builtin_bit_cast(short, h);
}
DEVI float bf2f(short s) {
  unsigned u = ((unsigned)(unsigned short)s) << 16;
  return __builtin_bit_cast(float, u);
}
DEVI void gload16(const void* g, void* l) {
  __builtin_amdgcn_global_load_lds((const __attribute__((address_space(1))) void*)g,
                                   (__attribute__((address_space(3))) void*)l, 16, 0, 0);
}
#define MFMA16(a, b, c) __builtin_amdgcn_mfma_f32_16x16x32_bf16((a), (b), (c), 0, 0, 0)

// ---------------- prep kernels ----------------

__global__ void cvt_bf16(const float* __restrict__ in, short* __restrict__ out, int n4) {
  int i = blockIdx.x * blockDim.x + threadIdx.x;
  if (i >= n4) return;
  float4 v = ((const float4*)in)[i];
  short4 o;
  o.x = f2bf(v.x); o.y = f2bf(v.y); o.z = f2bf(v.z); o.w = f2bf(v.w);
  ((short4*)out)[i] = o;
}

__global__ void rope_table(float2* __restrict__ tbl) {
  int i = blockIdx.x * blockDim.x + threadIdx.x;  // 2048*32
  int n = i >> 5, f = i & 31;
  float inv = powf(10000.0f, -(float)f * (1.0f / 32.0f));
  float ang = (float)n * inv;
  tbl[i] = make_float2(cosf(ang), sinf(ang));
}

// in-place RoPE on q (with scale) and k; layout (BH, N, D) bf16
__global__ void rope_apply(short* __restrict__ q, short* __restrict__ kk,
                           const float2* __restrict__ tbl) {
  int idx = blockIdx.x * blockDim.x + threadIdx.x;
  const int T = 64 * 2048 * 8;  // 16B chunks per tensor
  short* ptr; int i; float sc;
  if (idx < T) { ptr = q; i = idx; sc = 0.125f; }
  else         { ptr = kk; i = idx - T; sc = 1.0f; }
  int row = i >> 3, c8 = i & 7;
  int n = row & 2047;
  short* ad = ptr + (size_t)row * 64 + c8 * 8;
  short8v vv = *(short8v*)ad;
  short8v ov;
#pragma unroll
  for (int j = 0; j < 4; ++j) {
    float2 cs = tbl[n * 32 + c8 * 4 + j];
    float x0 = bf2f(vv[2 * j]), x1 = bf2f(vv[2 * j + 1]);
    ov[2 * j]     = f2bf((x0 * cs.x - x1 * cs.y) * sc);
    ov[2 * j + 1] = f2bf((x0 * cs.y + x1 * cs.x) * sc);
  }
  *(short8v*)ad = ov;
}

// ---------------- GEMM: C[M,N] = A[M,K] * B[N,K]^T + bias ----------------
// EPI=0: scatter to q/k/v (B,H,N,D) bf16.  EPI=1: f32 out [M,N].
template <int EPI>
__global__ __launch_bounds__(256)
void gemm_bt(const short* __restrict__ A, const short* __restrict__ Bw,
             const float* __restrict__ bias,
             short* __restrict__ q, short* __restrict__ k, short* __restrict__ v,
             float* __restrict__ fout, int Mdim, int Ndim, int Kdim) {
  __shared__ __attribute__((aligned(16))) short As[128 * 32];
  __shared__ __attribute__((aligned(16))) short Bs[128 * 32];
  const int t = threadIdx.x;
  const int lane = t & 63, w = t >> 6;
  const int wr = w >> 1, wc = w & 1;
  const int g = lane >> 4, r16 = lane & 15;
  const int m0 = blockIdx.y * 128, n0 = blockIdx.x * 128;

  f32x4 acc[4][4];
#pragma unroll
  for (int i = 0; i < 4; ++i)
#pragma unroll
    for (int j = 0; j < 4; ++j) acc[i][j] = (f32x4){0.f, 0.f, 0.f, 0.f};

  for (int k0 = 0; k0 < Kdim; k0 += 32) {
    __syncthreads();
#pragma unroll
    for (int p = 0; p < 2; ++p) {
      int c = p * 256 + t;
      int row = c >> 2, cc = c & 3;
      gload16(A + (size_t)(m0 + row) * Kdim + k0 + cc * 8, (char*)As + c * 16);
      gload16(Bw + (size_t)(n0 + row) * Kdim + k0 + cc * 8, (char*)Bs + c * 16);
    }
    __syncthreads();
    short8v af[4], bf[4];
#pragma unroll
    for (int mi = 0; mi < 4; ++mi)
      af[mi] = *(const short8v*)&As[(wr * 64 + mi * 16 + r16) * 32 + g * 8];
#pragma unroll
    for (int ni = 0; ni < 4; ++ni)
      bf[ni] = *(const short8v*)&Bs[(wc * 64 + ni * 16 + r16) * 32 + g * 8];
#pragma unroll
    for (int mi = 0; mi < 4; ++mi)
#pragma unroll
      for (int ni = 0; ni < 4; ++ni)
        acc[mi][ni] = MFMA16(af[mi], bf[ni], acc[mi][ni]);
  }

  if (EPI == 0) {
#pragma unroll
    for (int ni = 0; ni < 4; ++ni) {
      int col = n0 + wc * 64 + ni * 16 + r16;
      float bv = bias[col];
      int s = col >> 10, rr = col & 1023, h = rr >> 6, d = rr & 63;
      short* dst = (s == 0) ? q : (s == 1 ? k : v);
#pragma unroll
      for (int mi = 0; mi < 4; ++mi) {
        int mrow = m0 + wr * 64 + mi * 16 + g * 4;
#pragma unroll
        for (int r = 0; r < 4; ++r) {
          int m = mrow + r;
          int b = m >> 11, n = m & 2047;
          dst[((size_t)((b * 16 + h) * 2048 + n)) * 64 + d] = f2bf(acc[mi][ni][r] + bv);
        }
      }
    }
  } else {
#pragma unroll
    for (int ni = 0; ni < 4; ++ni) {
      int col = n0 + wc * 64 + ni * 16 + r16;
      float bv = bias[col];
#pragma unroll
      for (int mi = 0; mi < 4; ++mi) {
        int mrow = m0 + wr * 64 + mi * 16 + g * 4;
#pragma unroll
        for (int r = 0; r < 4; ++r)
          fout[(size_t)(mrow + r) * Ndim + col] = acc[mi][ni][r] + bv;
      }
    }
  }
}

// ---------------- causal flash attention ----------------
// q,k,v: (BH, N, D) bf16 (q pre-scaled). o: (B, N, H*D) bf16.
__global__ __launch_bounds__(256)
void fattn(const short* __restrict__ q, const short* __restrict__ k,
           const short* __restrict__ v, short* __restrict__ o) {
  const int qt = gridDim.x - 1 - blockIdx.x;  // heavy tiles first
  const int bh = blockIdx.y;
  const int b = bh >> 4, h = bh & 15;
  const int t = threadIdx.x, lane = t & 63, w = t >> 6;
  const int g = lane >> 4, r16 = lane & 15;
  __shared__ __attribute__((aligned(16))) short Ks[64 * 64];      // 16B-chunk XOR swizzled
  __shared__ __attribute__((aligned(16))) short Vt[64 * 72];      // transposed, col-block XOR
  __shared__ __attribute__((aligned(16))) short Ps[4][16 * 72];   // per-wave P

  const short* qb = q + (size_t)bh * 2048 * 64;
  const short* kb = k + (size_t)bh * 2048 * 64;
  const short* vb = v + (size_t)bh * 2048 * 64;

  short8v aq[2];
  {
    const short* qr = qb + (size_t)(qt * 64 + w * 16 + r16) * 64;
    aq[0] = *(const short8v*)(qr + g * 8);
    aq[1] = *(const short8v*)(qr + 32 + g * 8);
  }
  f32x4 oacc[4];
#pragma unroll
  for (int i = 0; i < 4; ++i) oacc[i] = (f32x4){0.f, 0.f, 0.f, 0.f};
  float mrun[4] = {-1e30f, -1e30f, -1e30f, -1e30f};
  float lrun[4] = {0.f, 0.f, 0.f, 0.f};

  for (int kt = 0; kt <= qt; ++kt) {
    __syncthreads();
    // K tile: global_load_lds, source pre-swizzled so LDS reads are conflict-free
#pragma unroll
    for (int p = 0; p < 2; ++p) {
      int c = p * 256 + t;
      int key = c >> 3, cc = c & 7;
      gload16((const char*)(kb + (size_t)(kt * 64 + key) * 64) + ((cc ^ (key & 7)) * 16),
              (char*)Ks + c * 16);
    }
    // V tile: transpose into LDS, column-block XOR swizzle
#pragma unroll
    for (int p = 0; p < 2; ++p) {
      int c = p * 256 + t;
      int key = c >> 3, d0 = (c & 7) * 8;
      short8v vv = *(const short8v*)(vb + (size_t)(kt * 64 + key) * 64 + d0);
#pragma unroll
      for (int j = 0; j < 8; ++j) {
        int d = d0 + j;
        Vt[d * 72 + (key ^ ((d >> 3) << 3))] = vv[j];
      }
    }
    __syncthreads();

    // S = (Q*scale) K^T : rows = q (g*4+r), cols = key (r16)
    f32x4 s[4];
#pragma unroll
    for (int kc = 0; kc < 4; ++kc) s[kc] = (f32x4){0.f, 0.f, 0.f, 0.f};
#pragma unroll
    for (int kc = 0; kc < 4; ++kc) {
      int key = kc * 16 + r16;
#pragma unroll
      for (int dc = 0; dc < 2; ++dc) {
        int cw = dc * 4 + g;
        short8v bk = *(const short8v*)((const char*)Ks + key * 128 + ((cw ^ (key & 7)) * 16));
        s[kc] = MFMA16(aq[dc], bk, s[kc]);
      }
    }

    const bool diag = (kt == qt);
#pragma unroll
    for (int r = 0; r < 4; ++r) {
      int qrow = w * 16 + g * 4 + r;
      if (diag) {
#pragma unroll
        for (int kc = 0; kc < 4; ++kc)
          if (kc * 16 + r16 > qrow) s[kc][r] = -1e30f;
      }
      float tm = fmaxf(fmaxf(s[0][r], s[1][r]), fmaxf(s[2][r], s[3][r]));
      tm = fmaxf(tm, __shfl_xor(tm, 1));
      tm = fmaxf(tm, __shfl_xor(tm, 2));
      tm = fmaxf(tm, __shfl_xor(tm, 4));
      tm = fmaxf(tm, __shfl_xor(tm, 8));
      float mnew = fmaxf(mrun[r], tm);
      float corr = __expf(mrun[r] - mnew);
      float rs = 0.f;
#pragma unroll
      for (int kc = 0; kc < 4; ++kc) {
        float pp = __expf(s[kc][r] - mnew);
        s[kc][r] = pp;
        rs += pp;
      }
      rs += __shfl_xor(rs, 1);
      rs += __shfl_xor(rs, 2);
      rs += __shfl_xor(rs, 4);
      rs += __shfl_xor(rs, 8);
      lrun[r] = lrun[r] * corr + rs;
      mrun[r] = mnew;
#pragma unroll
      for (int dc = 0; dc < 4; ++dc) oacc[dc][r] *= corr;
    }

    // P -> LDS (wave-private), then PV
    short* ps = &Ps[w][0];
#pragma unroll
    for (int kc = 0; kc < 4; ++kc)
#pragma unroll
      for (int r = 0; r < 4; ++r)
        ps[(g * 4 + r) * 72 + kc * 16 + r16] = f2bf(s[kc][r]);
    asm volatile("s_waitcnt lgkmcnt(0)" ::: "memory");
#pragma unroll
    for (int kk = 0; kk < 2; ++kk) {
      short8v ap = *(const short8v*)&ps[r16 * 72 + kk * 32 + g * 8];
#pragma unroll
      for (int dc = 0; dc < 4; ++dc) {
        int d = dc * 16 + r16;
        int blk = (kk * 4 + g) ^ (d >> 3);
        short8v bv = *(const short8v*)&Vt[d * 72 + blk * 8];
        oacc[dc] = MFMA16(ap, bv, oacc[dc]);
      }
    }
  }

  // epilogue: o[b, n, h*64 + d]
#pragma unroll
  for (int r = 0; r < 4; ++r) {
    float inv = 1.f / lrun[r];
    int n = qt * 64 + w * 16 + g * 4 + r;
    short* orow = o + ((size_t)(b * 2048 + n)) * 1024 + h * 64;
#pragma unroll
    for (int dc = 0; dc < 4; ++dc)
      orow[dc * 16 + r16] = f2bf(oacc[dc][r] * inv);
  }
}

// ---------------- launcher ----------------
extern "C" void kernel_launch(void* const* d_in, const int* in_sizes, int n_in,
                              void* d_out, int out_size, void* d_ws, size_t ws_size,
                              hipStream_t stream) {
  const float* x    = (const float*)d_in[0];
  const float* Wqkv = (const float*)d_in[1];
  const float* bqkv = (const float*)d_in[2];
  const float* Wout = (const float*)d_in[3];
  const float* bout = (const float*)d_in[4];

  char* p = (char*)d_ws;
  short* xb = (short*)p;    p += (size_t)8192 * 1024 * 2;   // x bf16; reused as attn output
  short* wqkvb = (short*)p; p += (size_t)3072 * 1024 * 2;
  short* woutb = (short*)p; p += (size_t)1024 * 1024 * 2;
  short* qbf = (short*)p;   p += (size_t)64 * 2048 * 64 * 2;
  short* kbf = (short*)p;   p += (size_t)64 * 2048 * 64 * 2;
  short* vbf = (short*)p;   p += (size_t)64 * 2048 * 64 * 2;
  float2* tbl = (float2*)p; p += (size_t)2048 * 32 * 8;

  cvt_bf16<<<8192, 256, 0, stream>>>(x, xb, 8192 * 1024 / 4);
  cvt_bf16<<<3072, 256, 0, stream>>>(Wqkv, wqkvb, 3072 * 1024 / 4);
  cvt_bf16<<<1024, 256, 0, stream>>>(Wout, woutb, 1024 * 1024 / 4);
  rope_table<<<256, 256, 0, stream>>>(tbl);

  gemm_bt<0><<<dim3(24, 64), 256, 0, stream>>>(xb, wqkvb, bqkv, qbf, kbf, vbf, nullptr,
                                               8192, 3072, 1024);
  rope_apply<<<8192, 256, 0, stream>>>(qbf, kbf, tbl);
  fattn<<<dim3(32, 64), 256, 0, stream>>>(qbf, kbf, vbf, xb);
  gemm_bt<1><<<dim3(8, 64), 256, 0, stream>>>(xb, woutb, bout, nullptr, nullptr, nullptr,
                                              (float*)d_out, 8192, 1024, 1024);
}

// Round 4
// 307.777 us; speedup vs baseline: 1.2463x; 1.2463x over previous
//
#include <hip/hip_runtime.h>
#include <hip/hip_bf16.h>

#define DEVI __device__ __forceinline__

typedef __attribute__((ext_vector_type(8))) short short8v;
typedef __attribute__((ext_vector_type(4))) float f32x4;
typedef __attribute__((ext_vector_type(2))) unsigned u32x2;

DEVI short f2bf(float f) {
  __hip_bfloat16 h = __float2bfloat16(f);
  return __builtin_bit_cast(short, h);
}
DEVI float bf2f(short s) {
  unsigned u = ((unsigned)(unsigned short)s) << 16;
  return __builtin_bit_cast(float, u);
}
DEVI unsigned packbf(float a, float b) {
  return (unsigned)(unsigned short)f2bf(a) | ((unsigned)(unsigned short)f2bf(b) << 16);
}
DEVI void gload16(const void* g, void* l) {
  __builtin_amdgcn_global_load_lds((const __attribute__((address_space(1))) void*)g,
                                   (__attribute__((address_space(3))) void*)l, 16, 0, 0);
}
#define MFMA16(a, b, c) __builtin_amdgcn_mfma_f32_16x16x32_bf16((a), (b), (c), 0, 0, 0)

// ---------------- prep kernels ----------------

__global__ void cvt_bf16(const float* __restrict__ in, short* __restrict__ out, int n4) {
  int i = blockIdx.x * blockDim.x + threadIdx.x;
  if (i >= n4) return;
  float4 v = ((const float4*)in)[i];
  short4 o;
  o.x = f2bf(v.x); o.y = f2bf(v.y); o.z = f2bf(v.z); o.w = f2bf(v.w);
  ((short4*)out)[i] = o;
}

__global__ void rope_table(float2* __restrict__ tbl) {
  int i = blockIdx.x * blockDim.x + threadIdx.x;  // 2048*32
  int n = i >> 5, f = i & 31;
  float inv = powf(10000.0f, -(float)f * (1.0f / 32.0f));
  float ang = (float)n * inv;
  tbl[i] = make_float2(cosf(ang), sinf(ang));
}

// in-place RoPE on q (scale folded with log2e for exp2-domain softmax) and k
__global__ void rope_apply(short* __restrict__ q, short* __restrict__ kk,
                           const float2* __restrict__ tbl) {
  int idx = blockIdx.x * blockDim.x + threadIdx.x;
  const int T = 64 * 2048 * 8;  // 16B chunks per tensor
  short* ptr; int i; float sc;
  if (idx < T) { ptr = q; i = idx; sc = 0.125f * 1.44269504088896f; }
  else         { ptr = kk; i = idx - T; sc = 1.0f; }
  int row = i >> 3, c8 = i & 7;
  int n = row & 2047;
  short* ad = ptr + (size_t)row * 64 + c8 * 8;
  short8v vv = *(short8v*)ad;
  short8v ov;
#pragma unroll
  for (int j = 0; j < 4; ++j) {
    float2 cs = tbl[n * 32 + c8 * 4 + j];
    float x0 = bf2f(vv[2 * j]), x1 = bf2f(vv[2 * j + 1]);
    ov[2 * j]     = f2bf((x0 * cs.x - x1 * cs.y) * sc);
    ov[2 * j + 1] = f2bf((x0 * cs.y + x1 * cs.x) * sc);
  }
  *(short8v*)ad = ov;
}

// ---------------- GEMM: C[M,N] = A[M,K] * B[N,K]^T + bias ----------------
template <int EPI>
__global__ __launch_bounds__(256)
void gemm_bt(const short* __restrict__ A, const short* __restrict__ Bw,
             const float* __restrict__ bias,
             short* __restrict__ q, short* __restrict__ k, short* __restrict__ v,
             float* __restrict__ fout, int Mdim, int Ndim, int Kdim) {
  __shared__ __attribute__((aligned(16))) short As[128 * 32];
  __shared__ __attribute__((aligned(16))) short Bs[128 * 32];
  const int t = threadIdx.x;
  const int lane = t & 63, w = t >> 6;
  const int wr = w >> 1, wc = w & 1;
  const int g = lane >> 4, r16 = lane & 15;
  const int m0 = blockIdx.y * 128, n0 = blockIdx.x * 128;

  f32x4 acc[4][4];
#pragma unroll
  for (int i = 0; i < 4; ++i)
#pragma unroll
    for (int j = 0; j < 4; ++j) acc[i][j] = (f32x4){0.f, 0.f, 0.f, 0.f};

  for (int k0 = 0; k0 < Kdim; k0 += 32) {
    __syncthreads();
#pragma unroll
    for (int p = 0; p < 2; ++p) {
      int c = p * 256 + t;
      int row = c >> 2, cc = c & 3;
      gload16(A + (size_t)(m0 + row) * Kdim + k0 + cc * 8, (char*)As + c * 16);
      gload16(Bw + (size_t)(n0 + row) * Kdim + k0 + cc * 8, (char*)Bs + c * 16);
    }
    __syncthreads();
    short8v af[4], bf[4];
#pragma unroll
    for (int mi = 0; mi < 4; ++mi)
      af[mi] = *(const short8v*)&As[(wr * 64 + mi * 16 + r16) * 32 + g * 8];
#pragma unroll
    for (int ni = 0; ni < 4; ++ni)
      bf[ni] = *(const short8v*)&Bs[(wc * 64 + ni * 16 + r16) * 32 + g * 8];
#pragma unroll
    for (int mi = 0; mi < 4; ++mi)
#pragma unroll
      for (int ni = 0; ni < 4; ++ni)
        acc[mi][ni] = MFMA16(af[mi], bf[ni], acc[mi][ni]);
  }

  if (EPI == 0) {
#pragma unroll
    for (int ni = 0; ni < 4; ++ni) {
      int col = n0 + wc * 64 + ni * 16 + r16;
      float bv = bias[col];
      int s = col >> 10, rr = col & 1023, h = rr >> 6, d = rr & 63;
      short* dst = (s == 0) ? q : (s == 1 ? k : v);
#pragma unroll
      for (int mi = 0; mi < 4; ++mi) {
        int mrow = m0 + wr * 64 + mi * 16 + g * 4;
#pragma unroll
        for (int r = 0; r < 4; ++r) {
          int m = mrow + r;
          int b = m >> 11, n = m & 2047;
          dst[((size_t)((b * 16 + h) * 2048 + n)) * 64 + d] = f2bf(acc[mi][ni][r] + bv);
        }
      }
    }
  } else {
#pragma unroll
    for (int ni = 0; ni < 4; ++ni) {
      int col = n0 + wc * 64 + ni * 16 + r16;
      float bv = bias[col];
#pragma unroll
      for (int mi = 0; mi < 4; ++mi) {
        int mrow = m0 + wr * 64 + mi * 16 + g * 4;
#pragma unroll
        for (int r = 0; r < 4; ++r)
          fout[(size_t)(mrow + r) * Ndim + col] = acc[mi][ni][r] + bv;
      }
    }
  }
}

// ---------------- causal flash attention (v2.2) ----------------
// q,k,v: (BH, N=2048, D=64) bf16; q pre-scaled by 0.125*log2e.
// o: (B, N, H*D) bf16.
// Block: 4 waves x 32 q-rows = 128 q-rows. KV tile = 64, double-buffered.
// Swapped QK^T: S^T = mfma(K, Q) -> lane holds q=r16, keys kc*16+g*4+r.
// V staged as round-0-verified transposed scatter Vt[d][key ^ blkXOR].
__global__ __launch_bounds__(256)
void fattn(const short* __restrict__ q, const short* __restrict__ k,
           const short* __restrict__ v, short* __restrict__ o) {
  const int qt = 15 - blockIdx.x;  // heavy tiles first
  const int bh = blockIdx.y;
  const int b = bh >> 4, h = bh & 15;
  const int t = threadIdx.x, lane = t & 63, w = t >> 6;
  const int g = lane >> 4, r16 = lane & 15;

  // K: row-major [key][64], 16B-unit XOR swizzle (unit ^= key&7)
  __shared__ __attribute__((aligned(16))) short Ks[2][64 * 64];
  // V transposed: [d][64 keys pad 72], key-block XOR by (d>>3)
  __shared__ __attribute__((aligned(16))) short Vt[2][64 * 72];
  // P: per-wave, per-qi [q=16][keys 64 pad 72]
  __shared__ __attribute__((aligned(16))) short Ps[4][2][16 * 72];

  const short* qb = q + (size_t)bh * 2048 * 64;
  const short* kb = k + (size_t)bh * 2048 * 64;
  const short* vb = v + (size_t)bh * 2048 * 64;

  const int q0 = qt * 128 + w * 32;

  // Q fragments (held in registers for whole block)
  short8v aq[2][2];
#pragma unroll
  for (int qi = 0; qi < 2; ++qi)
#pragma unroll
    for (int dk = 0; dk < 2; ++dk)
      aq[qi][dk] = *(const short8v*)(qb + (size_t)(q0 + qi * 16 + r16) * 64 + dk * 32 + g * 8);

  f32x4 oacc[2][4];
#pragma unroll
  for (int qi = 0; qi < 2; ++qi)
#pragma unroll
    for (int dc = 0; dc < 4; ++dc) oacc[qi][dc] = (f32x4){0.f, 0.f, 0.f, 0.f};
  float mrun[2] = {-1e30f, -1e30f};
  float lrun[2] = {0.f, 0.f};

  const int ktmax = 2 * qt + 1;

  short8v vreg[2];

  auto KSTAGE = [&](int s, int kt) {
    const short* kbt = kb + (size_t)kt * 64 * 64;
#pragma unroll
    for (int p = 0; p < 2; ++p) {
      int c = p * 256 + t;
      int key = c >> 3, u = c & 7;
      gload16(kbt + key * 64 + ((u ^ (key & 7)) * 8), (char*)&Ks[s][0] + c * 16);
    }
  };
  auto VLOAD = [&](int kt) {
    const short* vbt = vb + (size_t)kt * 64 * 64;
#pragma unroll
    for (int p = 0; p < 2; ++p) {
      int c = p * 256 + t;
      vreg[p] = *(const short8v*)(vbt + (c >> 3) * 64 + (c & 7) * 8);
    }
  };
  auto VSTORE = [&](int s) {
#pragma unroll
    for (int p = 0; p < 2; ++p) {
      int c = p * 256 + t;
      int key = c >> 3, d0 = (c & 7) * 8;
#pragma unroll
      for (int j = 0; j < 8; ++j) {
        int d = d0 + j;
        Vt[s][d * 72 + (key ^ ((d >> 3) << 3))] = vreg[p][j];
      }
    }
  };

  KSTAGE(0, 0);
  VLOAD(0);
  VSTORE(0);
  __syncthreads();

  for (int kt = 0; kt <= ktmax; ++kt) {
    const int cur = kt & 1;
    if (kt < ktmax) {
      KSTAGE(cur ^ 1, kt + 1);  // async global->LDS
      VLOAD(kt + 1);            // global->reg (T14 issue-early)
    }

    const bool act0 = (kt * 64 <= q0 + 15);
    const bool act1 = (kt * 64 <= q0 + 31);

    f32x4 s[2][4];
#pragma unroll
    for (int qi = 0; qi < 2; ++qi)
#pragma unroll
      for (int kc = 0; kc < 4; ++kc) s[qi][kc] = (f32x4){0.f, 0.f, 0.f, 0.f};

    if (act1) {
      // QK^T (swapped): A = K rows (key = kc*16+r16), B = Q
#pragma unroll
      for (int kc = 0; kc < 4; ++kc) {
        int key = kc * 16 + r16;
        const char* rb = (const char*)&Ks[cur][0] + key * 128;
        short8v kf0 = *(const short8v*)(rb + (((g) ^ (key & 7)) << 4));
        short8v kf1 = *(const short8v*)(rb + (((4 + g) ^ (key & 7)) << 4));
        if (act0) {
          s[0][kc] = MFMA16(kf0, aq[0][0], s[0][kc]);
          s[0][kc] = MFMA16(kf1, aq[0][1], s[0][kc]);
        }
        s[1][kc] = MFMA16(kf0, aq[1][0], s[1][kc]);
        s[1][kc] = MFMA16(kf1, aq[1][1], s[1][kc]);
      }

      // softmax (exp2 domain) + P pack/store per active qi
#pragma unroll
      for (int qi = 0; qi < 2; ++qi) {
        if (qi == 0 && !act0) continue;
        const int qrow = q0 + qi * 16 + r16;
        const bool needmask = (kt * 64 + 63 > q0 + qi * 16);
        if (needmask) {
#pragma unroll
          for (int kc = 0; kc < 4; ++kc)
#pragma unroll
            for (int r = 0; r < 4; ++r)
              if (kt * 64 + kc * 16 + g * 4 + r > qrow) s[qi][kc][r] = -1e30f;
        }
        float tm = s[qi][0][0];
#pragma unroll
        for (int kc = 0; kc < 4; ++kc)
#pragma unroll
          for (int r = 0; r < 4; ++r) tm = fmaxf(tm, s[qi][kc][r]);
        tm = fmaxf(tm, __shfl_xor(tm, 16));
        tm = fmaxf(tm, __shfl_xor(tm, 32));
        float m = mrun[qi];
        if (!__all(tm - m <= 8.0f)) {  // T13 defer-max
          float mnew = fmaxf(m, tm);
          float corr = __builtin_amdgcn_exp2f(m - mnew);
#pragma unroll
          for (int r = 0; r < 4; ++r) {
            float cr = __shfl(corr, (lane & 48) + g * 4 + r);
#pragma unroll
            for (int dc = 0; dc < 4; ++dc) oacc[qi][dc][r] *= cr;
          }
          lrun[qi] *= corr;
          mrun[qi] = mnew;
          m = mnew;
        }
        float rs = 0.f;
        unsigned pk[4][2];
#pragma unroll
        for (int kc = 0; kc < 4; ++kc) {
          float p0 = __builtin_amdgcn_exp2f(s[qi][kc][0] - m);
          float p1 = __builtin_amdgcn_exp2f(s[qi][kc][1] - m);
          float p2 = __builtin_amdgcn_exp2f(s[qi][kc][2] - m);
          float p3 = __builtin_amdgcn_exp2f(s[qi][kc][3] - m);
          rs += (p0 + p1) + (p2 + p3);
          pk[kc][0] = packbf(p0, p1);
          pk[kc][1] = packbf(p2, p3);
        }
        rs += __shfl_xor(rs, 16);
        rs += __shfl_xor(rs, 32);
        lrun[qi] += rs;
#pragma unroll
        for (int kc = 0; kc < 4; ++kc)
          *(u32x2*)((char*)&Ps[w][qi][0] + r16 * 144 + kc * 32 + g * 8) =
              (u32x2){pk[kc][0], pk[kc][1]};
      }

      asm volatile("" ::: "memory");  // order P stores before P loads

      // PV: A = P (rows q=r16), B = V rows from transposed Vt
      short8v pa[2][2];
#pragma unroll
      for (int qi = 0; qi < 2; ++qi) {
        if (qi == 0 && !act0) continue;
#pragma unroll
        for (int kk = 0; kk < 2; ++kk)
          pa[qi][kk] = *(const short8v*)((char*)&Ps[w][qi][0] + r16 * 144 + kk * 64 + g * 16);
      }
#pragma unroll
      for (int dc = 0; dc < 4; ++dc) {
        int d = dc * 16 + r16;
#pragma unroll
        for (int kk = 0; kk < 2; ++kk) {
          int blk = (kk * 4 + g) ^ (d >> 3);
          short8v bv = *(const short8v*)&Vt[cur][d * 72 + blk * 8];
          if (act0) oacc[0][dc] = MFMA16(pa[0][kk], bv, oacc[0][dc]);
          oacc[1][dc] = MFMA16(pa[1][kk], bv, oacc[1][dc]);
        }
      }
    }

    if (kt < ktmax) VSTORE(cur ^ 1);  // T14 write-late into next buffer
    __syncthreads();
  }

  // epilogue: O rows are q = q0 + qi*16 + g*4 + r; l lives at lane r16 -> shfl
#pragma unroll
  for (int qi = 0; qi < 2; ++qi) {
    float il = 1.f / lrun[qi];
#pragma unroll
    for (int r = 0; r < 4; ++r) {
      float ilr = __shfl(il, (lane & 48) + g * 4 + r);
      int qg = q0 + qi * 16 + g * 4 + r;
      short* orow = o + ((size_t)(b * 2048 + qg)) * 1024 + h * 64;
#pragma unroll
      for (int dc = 0; dc < 4; ++dc)
        orow[dc * 16 + r16] = f2bf(oacc[qi][dc][r] * ilr);
    }
  }
}

// ---------------- launcher ----------------
extern "C" void kernel_launch(void* const* d_in, const int* in_sizes, int n_in,
                              void* d_out, int out_size, void* d_ws, size_t ws_size,
                              hipStream_t stream) {
  const float* x    = (const float*)d_in[0];
  const float* Wqkv = (const float*)d_in[1];
  const float* bqkv = (const float*)d_in[2];
  const float* Wout = (const float*)d_in[3];
  const float* bout = (const float*)d_in[4];

  char* p = (char*)d_ws;
  short* xb = (short*)p;    p += (size_t)8192 * 1024 * 2;   // x bf16; reused as attn output
  short* wqkvb = (short*)p; p += (size_t)3072 * 1024 * 2;
  short* woutb = (short*)p; p += (size_t)1024 * 1024 * 2;
  short* qbf = (short*)p;   p += (size_t)64 * 2048 * 64 * 2;
  short* kbf = (short*)p;   p += (size_t)64 * 2048 * 64 * 2;
  short* vbf = (short*)p;   p += (size_t)64 * 2048 * 64 * 2;
  float2* tbl = (float2*)p; p += (size_t)2048 * 32 * 8;

  cvt_bf16<<<8192, 256, 0, stream>>>(x, xb, 8192 * 1024 / 4);
  cvt_bf16<<<3072, 256, 0, stream>>>(Wqkv, wqkvb, 3072 * 1024 / 4);
  cvt_bf16<<<1024, 256, 0, stream>>>(Wout, woutb, 1024 * 1024 / 4);
  rope_table<<<256, 256, 0, stream>>>(tbl);

  gemm_bt<0><<<dim3(24, 64), 256, 0, stream>>>(xb, wqkvb, bqkv, qbf, kbf, vbf, nullptr,
                                               8192, 3072, 1024);
  rope_apply<<<8192, 256, 0, stream>>>(qbf, kbf, tbl);
  fattn<<<dim3(16, 64), 256, 0, stream>>>(qbf, kbf, vbf, xb);
  gemm_bt<1><<<dim3(8, 64), 256, 0, stream>>>(xb, woutb, bout, nullptr, nullptr, nullptr,
                                              (float*)d_out, 8192, 1024, 1024);
}

// Round 5
// 250.338 us; speedup vs baseline: 1.5323x; 1.2294x over previous
//
#include <hip/hip_runtime.h>
#include <hip/hip_bf16.h>

#define DEVI __device__ __forceinline__

typedef __attribute__((ext_vector_type(8))) short short8v;
typedef __attribute__((ext_vector_type(4))) float f32x4;
typedef __attribute__((ext_vector_type(2))) unsigned u32x2;

DEVI short f2bf(float f) {
  __hip_bfloat16 h = __float2bfloat16(f);
  return __builtin_bit_cast(short, h);
}
DEVI float bf2f(short s) {
  unsigned u = ((unsigned)(unsigned short)s) << 16;
  return __builtin_bit_cast(float, u);
}
DEVI unsigned packbf(float a, float b) {
  return (unsigned)(unsigned short)f2bf(a) | ((unsigned)(unsigned short)f2bf(b) << 16);
}
DEVI void gload16(const void* g, void* l) {
  __builtin_amdgcn_global_load_lds((const __attribute__((address_space(1))) void*)g,
                                   (__attribute__((address_space(3))) void*)l, 16, 0, 0);
}
#define MFMA16(a, b, c) __builtin_amdgcn_mfma_f32_16x16x32_bf16((a), (b), (c), 0, 0, 0)

// ---------------- prep kernels ----------------

__global__ void cvt_bf16(const float* __restrict__ in, short* __restrict__ out, int n4) {
  int i = blockIdx.x * blockDim.x + threadIdx.x;
  if (i >= n4) return;
  float4 v = ((const float4*)in)[i];
  short4 o;
  o.x = f2bf(v.x); o.y = f2bf(v.y); o.z = f2bf(v.z); o.w = f2bf(v.w);
  ((short4*)out)[i] = o;
}

__global__ void rope_table(float2* __restrict__ tbl) {
  int i = blockIdx.x * blockDim.x + threadIdx.x;  // 2048*32
  int n = i >> 5, f = i & 31;
  float inv = powf(10000.0f, -(float)f * (1.0f / 32.0f));
  float ang = (float)n * inv;
  tbl[i] = make_float2(cosf(ang), sinf(ang));
}

// in-place RoPE on q (scale folded with log2e for exp2-domain softmax) and k
__global__ void rope_apply(short* __restrict__ q, short* __restrict__ kk,
                           const float2* __restrict__ tbl) {
  int idx = blockIdx.x * blockDim.x + threadIdx.x;
  const int T = 64 * 2048 * 8;  // 16B chunks per tensor
  short* ptr; int i; float sc;
  if (idx < T) { ptr = q; i = idx; sc = 0.125f * 1.44269504088896f; }
  else         { ptr = kk; i = idx - T; sc = 1.0f; }
  int row = i >> 3, c8 = i & 7;
  int n = row & 2047;
  short* ad = ptr + (size_t)row * 64 + c8 * 8;
  short8v vv = *(short8v*)ad;
  short8v ov;
#pragma unroll
  for (int j = 0; j < 4; ++j) {
    float2 cs = tbl[n * 32 + c8 * 4 + j];
    float x0 = bf2f(vv[2 * j]), x1 = bf2f(vv[2 * j + 1]);
    ov[2 * j]     = f2bf((x0 * cs.x - x1 * cs.y) * sc);
    ov[2 * j + 1] = f2bf((x0 * cs.y + x1 * cs.x) * sc);
  }
  *(short8v*)ad = ov;
}

// ---------------- GEMM: C[M,N] = A[M,K] * B[N,K]^T + bias ----------------
// EPI=0: scatter q,k as (BH,N,D); v TRANSPOSED as (BH,D,N).  EPI=1: f32 [M,N].
template <int EPI>
__global__ __launch_bounds__(256)
void gemm_bt(const short* __restrict__ A, const short* __restrict__ Bw,
             const float* __restrict__ bias,
             short* __restrict__ q, short* __restrict__ k, short* __restrict__ v,
             float* __restrict__ fout, int Mdim, int Ndim, int Kdim) {
  __shared__ __attribute__((aligned(16))) short As[128 * 32];
  __shared__ __attribute__((aligned(16))) short Bs[128 * 32];
  const int t = threadIdx.x;
  const int lane = t & 63, w = t >> 6;
  const int wr = w >> 1, wc = w & 1;
  const int g = lane >> 4, r16 = lane & 15;
  const int m0 = blockIdx.y * 128, n0 = blockIdx.x * 128;

  f32x4 acc[4][4];
#pragma unroll
  for (int i = 0; i < 4; ++i)
#pragma unroll
    for (int j = 0; j < 4; ++j) acc[i][j] = (f32x4){0.f, 0.f, 0.f, 0.f};

  for (int k0 = 0; k0 < Kdim; k0 += 32) {
    __syncthreads();
#pragma unroll
    for (int p = 0; p < 2; ++p) {
      int c = p * 256 + t;
      int row = c >> 2, cc = c & 3;
      gload16(A + (size_t)(m0 + row) * Kdim + k0 + cc * 8, (char*)As + c * 16);
      gload16(Bw + (size_t)(n0 + row) * Kdim + k0 + cc * 8, (char*)Bs + c * 16);
    }
    __syncthreads();
    short8v af[4], bf[4];
#pragma unroll
    for (int mi = 0; mi < 4; ++mi)
      af[mi] = *(const short8v*)&As[(wr * 64 + mi * 16 + r16) * 32 + g * 8];
#pragma unroll
    for (int ni = 0; ni < 4; ++ni)
      bf[ni] = *(const short8v*)&Bs[(wc * 64 + ni * 16 + r16) * 32 + g * 8];
#pragma unroll
    for (int mi = 0; mi < 4; ++mi)
#pragma unroll
      for (int ni = 0; ni < 4; ++ni)
        acc[mi][ni] = MFMA16(af[mi], bf[ni], acc[mi][ni]);
  }

  if (EPI == 0) {
#pragma unroll
    for (int ni = 0; ni < 4; ++ni) {
      int col = n0 + wc * 64 + ni * 16 + r16;
      float bv = bias[col];
      int s = col >> 10, rr = col & 1023, h = rr >> 6, d = rr & 63;
      short* dst = (s == 0) ? q : (s == 1 ? k : v);
      const bool vt = (s == 2);
#pragma unroll
      for (int mi = 0; mi < 4; ++mi) {
        int mrow = m0 + wr * 64 + mi * 16 + g * 4;
#pragma unroll
        for (int r = 0; r < 4; ++r) {
          int m = mrow + r;
          int b = m >> 11, n = m & 2047;
          size_t idx = vt ? ((((size_t)(b * 16 + h)) * 64 + d) * 2048 + n)
                          : ((((size_t)(b * 16 + h)) * 2048 + n) * 64 + d);
          dst[idx] = f2bf(acc[mi][ni][r] + bv);
        }
      }
    }
  } else {
#pragma unroll
    for (int ni = 0; ni < 4; ++ni) {
      int col = n0 + wc * 64 + ni * 16 + r16;
      float bv = bias[col];
#pragma unroll
      for (int mi = 0; mi < 4; ++mi) {
        int mrow = m0 + wr * 64 + mi * 16 + g * 4;
#pragma unroll
        for (int r = 0; r < 4; ++r)
          fout[(size_t)(mrow + r) * Ndim + col] = acc[mi][ni][r] + bv;
      }
    }
  }
}

// ---------------- causal flash attention (v3) ----------------
// q,k: (BH, N=2048, D=64) bf16 (q pre-scaled by 0.125*log2e); vT: (BH, D=64, N).
// o: (B, N, H*D) bf16.
// Block: 4 waves x 32 q-rows = 128 q-rows per q-tile; each block runs TWO
// paired q-tiles (15-pq, pq) for equal causal work. KV tile = 64, dbuf.
// Swapped QK^T: S^T = mfma(K, Q) -> lane holds q=r16, keys kc*16+g*4+r.
// K and vT both staged via global_load_lds with 16B-unit XOR swizzle.
__global__ __launch_bounds__(256)
void fattn(const short* __restrict__ q, const short* __restrict__ k,
           const short* __restrict__ vT, short* __restrict__ o) {
  const int pq = blockIdx.x;  // 0..7
  const int bh = blockIdx.y;
  const int b = bh >> 4, h = bh & 15;
  const int t = threadIdx.x, lane = t & 63, w = t >> 6;
  const int g = lane >> 4, r16 = lane & 15;

  // K: [key][64], 16B-unit XOR swizzle (unit ^= key&7)
  __shared__ __attribute__((aligned(16))) short Ks[2][64 * 64];
  // V^T: [d][64 keys], 16B-unit XOR swizzle (unit ^= d&7)
  __shared__ __attribute__((aligned(16))) short Vt[2][64 * 64];
  // P: per-wave, per-qi [q=16][keys 64 pad 72]
  __shared__ __attribute__((aligned(16))) short Ps[4][2][16 * 72];

  const short* qb = q + (size_t)bh * 2048 * 64;
  const short* kb = k + (size_t)bh * 2048 * 64;
  const short* vb = vT + (size_t)bh * 2048 * 64;

  auto STAGE = [&](int s, int kt) {
    const short* kbt = kb + (size_t)kt * 64 * 64;
    const short* vbt = vb + kt * 64;
#pragma unroll
    for (int p = 0; p < 2; ++p) {
      int c = p * 256 + t;
      int row = c >> 3, u = c & 7;
      gload16(kbt + row * 64 + ((u ^ (row & 7)) * 8), (char*)&Ks[s][0] + c * 16);
      gload16(vbt + (size_t)row * 2048 + ((u ^ (row & 7)) * 8), (char*)&Vt[s][0] + c * 16);
    }
  };

  for (int half = 0; half < 2; ++half) {
    const int qt = half ? pq : (15 - pq);
    const int q0 = qt * 128 + w * 32;

    // Q fragments
    short8v aq[2][2];
#pragma unroll
    for (int qi = 0; qi < 2; ++qi)
#pragma unroll
      for (int dk = 0; dk < 2; ++dk)
        aq[qi][dk] =
            *(const short8v*)(qb + (size_t)(q0 + qi * 16 + r16) * 64 + dk * 32 + g * 8);

    f32x4 oacc[2][4];
#pragma unroll
    for (int qi = 0; qi < 2; ++qi)
#pragma unroll
      for (int dc = 0; dc < 4; ++dc) oacc[qi][dc] = (f32x4){0.f, 0.f, 0.f, 0.f};
    float mrun[2] = {-1e30f, -1e30f};
    float lrun[2] = {0.f, 0.f};

    const int ktmax = 2 * qt + 1;

    STAGE(0, 0);
    __syncthreads();

    for (int kt = 0; kt <= ktmax; ++kt) {
      const int cur = kt & 1;
      if (kt < ktmax) STAGE(cur ^ 1, kt + 1);

      const bool act0 = (kt * 64 <= q0 + 15);
      const bool act1 = (kt * 64 <= q0 + 31);

      f32x4 s[2][4];
#pragma unroll
      for (int qi = 0; qi < 2; ++qi)
#pragma unroll
        for (int kc = 0; kc < 4; ++kc) s[qi][kc] = (f32x4){0.f, 0.f, 0.f, 0.f};

      if (act1) {
        // QK^T (swapped): A = K rows (key = kc*16+r16), B = Q
#pragma unroll
        for (int kc = 0; kc < 4; ++kc) {
          int key = kc * 16 + r16;
          const char* rb = (const char*)&Ks[cur][0] + key * 128;
          short8v kf0 = *(const short8v*)(rb + (((g) ^ (key & 7)) << 4));
          short8v kf1 = *(const short8v*)(rb + (((4 + g) ^ (key & 7)) << 4));
          if (act0) {
            s[0][kc] = MFMA16(kf0, aq[0][0], s[0][kc]);
            s[0][kc] = MFMA16(kf1, aq[0][1], s[0][kc]);
          }
          s[1][kc] = MFMA16(kf0, aq[1][0], s[1][kc]);
          s[1][kc] = MFMA16(kf1, aq[1][1], s[1][kc]);
        }

        // softmax (exp2 domain) + P pack/store per active qi
#pragma unroll
        for (int qi = 0; qi < 2; ++qi) {
          if (qi == 0 && !act0) continue;
          const int qrow = q0 + qi * 16 + r16;
          const bool needmask = (kt * 64 + 63 > q0 + qi * 16);
          if (needmask) {
#pragma unroll
            for (int kc = 0; kc < 4; ++kc)
#pragma unroll
              for (int r = 0; r < 4; ++r)
                if (kt * 64 + kc * 16 + g * 4 + r > qrow) s[qi][kc][r] = -1e30f;
          }
          float tm = s[qi][0][0];
#pragma unroll
          for (int kc = 0; kc < 4; ++kc)
#pragma unroll
            for (int r = 0; r < 4; ++r) tm = fmaxf(tm, s[qi][kc][r]);
          tm = fmaxf(tm, __shfl_xor(tm, 16));
          tm = fmaxf(tm, __shfl_xor(tm, 32));
          float m = mrun[qi];
          if (!__all(tm - m <= 8.0f)) {  // T13 defer-max
            float mnew = fmaxf(m, tm);
            float corr = __builtin_amdgcn_exp2f(m - mnew);
#pragma unroll
            for (int r = 0; r < 4; ++r) {
              float cr = __shfl(corr, (lane & 48) + g * 4 + r);
#pragma unroll
              for (int dc = 0; dc < 4; ++dc) oacc[qi][dc][r] *= cr;
            }
            lrun[qi] *= corr;
            mrun[qi] = mnew;
            m = mnew;
          }
          float rs = 0.f;
          unsigned pk[4][2];
#pragma unroll
          for (int kc = 0; kc < 4; ++kc) {
            float p0 = __builtin_amdgcn_exp2f(s[qi][kc][0] - m);
            float p1 = __builtin_amdgcn_exp2f(s[qi][kc][1] - m);
            float p2 = __builtin_amdgcn_exp2f(s[qi][kc][2] - m);
            float p3 = __builtin_amdgcn_exp2f(s[qi][kc][3] - m);
            rs += (p0 + p1) + (p2 + p3);
            pk[kc][0] = packbf(p0, p1);
            pk[kc][1] = packbf(p2, p3);
          }
          rs += __shfl_xor(rs, 16);
          rs += __shfl_xor(rs, 32);
          lrun[qi] += rs;
#pragma unroll
          for (int kc = 0; kc < 4; ++kc)
            *(u32x2*)((char*)&Ps[w][qi][0] + r16 * 144 + kc * 32 + g * 8) =
                (u32x2){pk[kc][0], pk[kc][1]};
        }

        asm volatile("" ::: "memory");  // order P stores before P loads

        // PV: A = P (rows q=r16), B fragment = vT rows d, keys kk*32+g*8..+7
        short8v pa[2][2];
#pragma unroll
        for (int qi = 0; qi < 2; ++qi) {
          if (qi == 0 && !act0) continue;
#pragma unroll
          for (int kk = 0; kk < 2; ++kk)
            pa[qi][kk] =
                *(const short8v*)((char*)&Ps[w][qi][0] + r16 * 144 + kk * 64 + g * 16);
        }
#pragma unroll
        for (int dc = 0; dc < 4; ++dc) {
          int d = dc * 16 + r16;
          const char* vr = (const char*)&Vt[cur][0] + d * 128;
#pragma unroll
          for (int kk = 0; kk < 2; ++kk) {
            short8v bv = *(const short8v*)(vr + (((kk * 4 + g) ^ (d & 7)) << 4));
            if (act0) oacc[0][dc] = MFMA16(pa[0][kk], bv, oacc[0][dc]);
            oacc[1][dc] = MFMA16(pa[1][kk], bv, oacc[1][dc]);
          }
        }
      }
      __syncthreads();
    }

    // epilogue: O rows are q = q0 + qi*16 + g*4 + r; l lives at lane r16 -> shfl
#pragma unroll
    for (int qi = 0; qi < 2; ++qi) {
      float il = 1.f / lrun[qi];
#pragma unroll
      for (int r = 0; r < 4; ++r) {
        float ilr = __shfl(il, (lane & 48) + g * 4 + r);
        int qg = q0 + qi * 16 + g * 4 + r;
        short* orow = o + ((size_t)(b * 2048 + qg)) * 1024 + h * 64;
#pragma unroll
        for (int dc = 0; dc < 4; ++dc)
          orow[dc * 16 + r16] = f2bf(oacc[qi][dc][r] * ilr);
      }
    }
  }
}

// ---------------- launcher ----------------
extern "C" void kernel_launch(void* const* d_in, const int* in_sizes, int n_in,
                              void* d_out, int out_size, void* d_ws, size_t ws_size,
                              hipStream_t stream) {
  const float* x    = (const float*)d_in[0];
  const float* Wqkv = (const float*)d_in[1];
  const float* bqkv = (const float*)d_in[2];
  const float* Wout = (const float*)d_in[3];
  const float* bout = (const float*)d_in[4];

  char* p = (char*)d_ws;
  short* xb = (short*)p;    p += (size_t)8192 * 1024 * 2;   // x bf16; reused as attn output
  short* wqkvb = (short*)p; p += (size_t)3072 * 1024 * 2;
  short* woutb = (short*)p; p += (size_t)1024 * 1024 * 2;
  short* qbf = (short*)p;   p += (size_t)64 * 2048 * 64 * 2;
  short* kbf = (short*)p;   p += (size_t)64 * 2048 * 64 * 2;
  short* vbf = (short*)p;   p += (size_t)64 * 2048 * 64 * 2;  // vT (BH, D, N)
  float2* tbl = (float2*)p; p += (size_t)2048 * 32 * 8;

  cvt_bf16<<<8192, 256, 0, stream>>>(x, xb, 8192 * 1024 / 4);
  cvt_bf16<<<3072, 256, 0, stream>>>(Wqkv, wqkvb, 3072 * 1024 / 4);
  cvt_bf16<<<1024, 256, 0, stream>>>(Wout, woutb, 1024 * 1024 / 4);
  rope_table<<<256, 256, 0, stream>>>(tbl);

  gemm_bt<0><<<dim3(24, 64), 256, 0, stream>>>(xb, wqkvb, bqkv, qbf, kbf, vbf, nullptr,
                                               8192, 3072, 1024);
  rope_apply<<<8192, 256, 0, stream>>>(qbf, kbf, tbl);
  fattn<<<dim3(8, 64), 256, 0, stream>>>(qbf, kbf, vbf, xb);
  gemm_bt<1><<<dim3(8, 64), 256, 0, stream>>>(xb, woutb, bout, nullptr, nullptr, nullptr,
                                              (float*)d_out, 8192, 1024, 1024);
}